// Round 9
// baseline (509.944 us; speedup 1.0000x reference)
//
#include <hip/hip_runtime.h>
#include <math.h>
#include <stdint.h>

#define DIM 768
#define SEQ 4096
#define BATCH 4
#define TOK (BATCH*SEQ)

typedef _Float16 f16;
typedef _Float16 f16x8 __attribute__((ext_vector_type(8)));
typedef _Float16 f16x4 __attribute__((ext_vector_type(4)));
typedef float f32x4 __attribute__((ext_vector_type(4)));

// async global->LDS, 16B per lane; LDS dest is wave-uniform base + lane*16
#define GLOAD16(gp, lp) __builtin_amdgcn_global_load_lds( \
    (const __attribute__((address_space(1))) unsigned int*)(gp), \
    (__attribute__((address_space(3))) unsigned int*)(lp), 16, 0, 0)

// XCD-aware bijective block swizzle (T1, m157/m204): contiguous grid chunk per XCD.
// Requires gx*gridDim.y % 8 == 0 (true for all our grids). gx must be a pow2 literal.
__device__ __forceinline__ void xcd_swizzle(int gx, int& bx, int& by) {
    int orig = blockIdx.x + gx * blockIdx.y;
    int nwg  = gx * gridDim.y;
    int swz  = (orig & 7) * (nwg >> 3) + (orig >> 3);
    bx = swz & (gx - 1);
    by = swz / gx;
}

// ---------------- fp32 -> fp16 convert ----------------
__global__ void cvt_kernel(const float* __restrict__ src, f16* __restrict__ dst, int n4) {
    int i = blockIdx.x * blockDim.x + threadIdx.x;
    int stride = gridDim.x * blockDim.x;
    for (; i < n4; i += stride) {
        float4 v = ((const float4*)src)[i];
        f16x4 h = { (f16)v.x, (f16)v.y, (f16)v.z, (f16)v.w };
        ((f16x4*)dst)[i] = h;
    }
}

__global__ void zero_kernel(float* __restrict__ p, int n) {
    int i = blockIdx.x * blockDim.x + threadIdx.x;
    if (i < n) p[i] = 0.f;
}

// ---------------- QKV projection GEMM (BK=64 two-subtile, XCD swizzle) ----------------
__launch_bounds__(256, 4)
__global__ void proj_kernel4(const f16* __restrict__ xh, const f16* __restrict__ Wh,
                             const float* __restrict__ bq, const float* __restrict__ bk,
                             const float* __restrict__ bv,
                             f16* __restrict__ Qh, f16* __restrict__ Kh,
                             f16* __restrict__ Vd, int vscatter) {
    __shared__ __align__(16) char lds[32768];
    f16* As0 = (f16*)lds;
    f16* As1 = (f16*)(lds + 8192);
    f16* Bs0 = (f16*)(lds + 16384);
    f16* Bs1 = (f16*)(lds + 24576);
    typedef f16 repRow[136];
    repRow* rep = (repRow*)lds;

    int bx, by;
    xcd_swizzle(128, bx, by);

    int tid = threadIdx.x;
    int w = tid >> 6, l = tid & 63;
    int wr = w >> 1, wc = w & 1;
    int lr = l & 15, lq = l >> 4;
    int srow = l >> 2, skg = (l & 3) * 8;

    const f16* Abase = xh + (size_t)bx * 128 * DIM;
    const f16* Bbase = Wh + (size_t)by * 128 * DIM;

    f32x4 acc[4][4] = {};
    for (int k0 = 0; k0 < DIM; k0 += 64) {
        __syncthreads();
        GLOAD16(Abase + (size_t)(w*16 + srow)*DIM + k0 + skg,          As0 + w*512);
        GLOAD16(Abase + (size_t)((4+w)*16 + srow)*DIM + k0 + skg,      As0 + (4+w)*512);
        GLOAD16(Abase + (size_t)(w*16 + srow)*DIM + k0 + 32 + skg,     As1 + w*512);
        GLOAD16(Abase + (size_t)((4+w)*16 + srow)*DIM + k0 + 32 + skg, As1 + (4+w)*512);
        GLOAD16(Bbase + (size_t)(w*16 + srow)*DIM + k0 + skg,          Bs0 + w*512);
        GLOAD16(Bbase + (size_t)((4+w)*16 + srow)*DIM + k0 + skg,      Bs0 + (4+w)*512);
        GLOAD16(Bbase + (size_t)(w*16 + srow)*DIM + k0 + 32 + skg,     Bs1 + w*512);
        GLOAD16(Bbase + (size_t)((4+w)*16 + srow)*DIM + k0 + 32 + skg, Bs1 + (4+w)*512);
        __syncthreads();
        f16x8 a0[4], b0[4], a1[4], b1[4];
#pragma unroll
        for (int mt = 0; mt < 4; ++mt) {
            a0[mt] = *(const f16x8*)&As0[(wr*64 + mt*16 + lr)*32 + lq*8];
            a1[mt] = *(const f16x8*)&As1[(wr*64 + mt*16 + lr)*32 + lq*8];
        }
#pragma unroll
        for (int nt = 0; nt < 4; ++nt) {
            b0[nt] = *(const f16x8*)&Bs0[(wc*64 + nt*16 + lr)*32 + lq*8];
            b1[nt] = *(const f16x8*)&Bs1[(wc*64 + nt*16 + lr)*32 + lq*8];
        }
#pragma unroll
        for (int mt = 0; mt < 4; ++mt)
#pragma unroll
            for (int nt = 0; nt < 4; ++nt) {
                acc[mt][nt] = __builtin_amdgcn_mfma_f32_16x16x32_f16(a0[mt], b0[nt], acc[mt][nt], 0, 0, 0);
                acc[mt][nt] = __builtin_amdgcn_mfma_f32_16x16x32_f16(a1[mt], b1[nt], acc[mt][nt], 0, 0, 0);
            }
    }

    int mat = by / 6;
    int e0  = (by - mat*6) * 128;
    const float* bias = (mat == 0) ? bq : ((mat == 1) ? bk : bv);
    float be[4];
#pragma unroll
    for (int nt = 0; nt < 4; ++nt) be[nt] = bias[e0 + wc*64 + nt*16 + lr];

    int trow0 = bx * 128;

    if (mat == 2 && vscatter) {
#pragma unroll
        for (int nt = 0; nt < 4; ++nt) {
            int e = e0 + wc*64 + nt*16 + lr;
#pragma unroll
            for (int mt = 0; mt < 4; ++mt)
#pragma unroll
                for (int q = 0; q < 4; ++q) {
                    int t = trow0 + wr*64 + mt*16 + lq*4 + q;
                    Vd[((size_t)(t >> 12) * DIM + e) * SEQ + (t & (SEQ - 1))] =
                        (f16)(acc[mt][nt][q] + be[nt]);
                }
        }
        return;
    }

    f16* dst = (mat == 0) ? Qh : ((mat == 1) ? Kh : Vd);
#pragma unroll
    for (int ph = 0; ph < 2; ++ph) {
        __syncthreads();
        if (wr == ph) {
#pragma unroll
            for (int mt = 0; mt < 4; ++mt)
#pragma unroll
                for (int nt = 0; nt < 4; ++nt)
#pragma unroll
                    for (int q = 0; q < 4; ++q)
                        rep[mt*16 + lq*4 + q][wc*64 + nt*16 + lr] = (f16)(acc[mt][nt][q] + be[nt]);
        }
        __syncthreads();
        int row = tid >> 2, cg = (tid & 3) * 4;
        f16* drow = dst + (size_t)(trow0 + ph*64 + row) * DIM + e0;
        const f16* srcr = rep[row];
#pragma unroll
        for (int j = 0; j < 4; ++j)
            *(f16x8*)(drow + (cg + j)*8) = *(const f16x8*)(srcr + (cg + j)*8);
    }
}

// ---------------- V row-major -> VT transpose (64x64 LDS tiles) ----------------
__launch_bounds__(256)
__global__ void transpose_v(const f16* __restrict__ Vr, f16* __restrict__ VT) {
    __shared__ f16 t[64][72];
    int tid = threadIdx.x;
    int b = blockIdx.z, s0 = blockIdx.x * 64, d0 = blockIdx.y * 64;
    int r = tid >> 2, c4 = tid & 3;
    const f16* src = Vr + ((size_t)b * SEQ + s0 + r) * DIM + d0;
    *(f16x8*)&t[r][c4*8]     = *(const f16x8*)(src + c4*8);
    *(f16x8*)&t[r][(c4+4)*8] = *(const f16x8*)(src + (c4+4)*8);
    __syncthreads();
    int rd = tid >> 2;
    f16* dst = VT + ((size_t)b * DIM + d0 + rd) * SEQ + s0;
#pragma unroll
    for (int c = c4; c < 8; c += 4) {
        f16x8 v;
#pragma unroll
        for (int j = 0; j < 8; ++j) v[j] = t[c*8 + j][rd];
        *(f16x8*)(dst + c*8) = v;
    }
}

// ---------------- S = Q K^T (128^2, BK=64 two-subtile, XCD swizzle) ----------------
__launch_bounds__(256, 4)
__global__ void qkt_kernel4(const f16* __restrict__ Qh, const f16* __restrict__ Kh,
                            f16* __restrict__ Sc, int c0, int ch) {
    __shared__ __align__(16) char lds[32768];
    f16* As0 = (f16*)lds;
    f16* As1 = (f16*)(lds + 8192);
    f16* Bs0 = (f16*)(lds + 16384);
    f16* Bs1 = (f16*)(lds + 24576);
    typedef f16 repRow[136];
    repRow* rep = (repRow*)lds;

    int bx, by;
    if (gridDim.x == 32)      xcd_swizzle(32, bx, by);
    else if (gridDim.x == 16) xcd_swizzle(16, bx, by);
    else                      xcd_swizzle(8,  bx, by);

    int tid = threadIdx.x;
    int w = tid >> 6, l = tid & 63;
    int wr = w >> 1, wc = w & 1;
    int lr = l & 15, lq = l >> 4;
    int srow = l >> 2, skg = (l & 3) * 8;
    int b = blockIdx.z;

    const f16* Abase = Qh + ((size_t)b * SEQ + c0 + bx * 128) * DIM;
    const f16* Bbase = Kh + (size_t)b * SEQ * DIM + (size_t)by * 128 * DIM;

    f32x4 acc[4][4] = {};
    for (int k0 = 0; k0 < DIM; k0 += 64) {
        __syncthreads();
        GLOAD16(Abase + (size_t)(w*16 + srow)*DIM + k0 + skg,          As0 + w*512);
        GLOAD16(Abase + (size_t)((4+w)*16 + srow)*DIM + k0 + skg,      As0 + (4+w)*512);
        GLOAD16(Abase + (size_t)(w*16 + srow)*DIM + k0 + 32 + skg,     As1 + w*512);
        GLOAD16(Abase + (size_t)((4+w)*16 + srow)*DIM + k0 + 32 + skg, As1 + (4+w)*512);
        GLOAD16(Bbase + (size_t)(w*16 + srow)*DIM + k0 + skg,          Bs0 + w*512);
        GLOAD16(Bbase + (size_t)((4+w)*16 + srow)*DIM + k0 + skg,      Bs0 + (4+w)*512);
        GLOAD16(Bbase + (size_t)(w*16 + srow)*DIM + k0 + 32 + skg,     Bs1 + w*512);
        GLOAD16(Bbase + (size_t)((4+w)*16 + srow)*DIM + k0 + 32 + skg, Bs1 + (4+w)*512);
        __syncthreads();
        f16x8 a0[4], b0[4], a1[4], b1[4];
#pragma unroll
        for (int mt = 0; mt < 4; ++mt) {
            a0[mt] = *(const f16x8*)&As0[(wr*64 + mt*16 + lr)*32 + lq*8];
            a1[mt] = *(const f16x8*)&As1[(wr*64 + mt*16 + lr)*32 + lq*8];
        }
#pragma unroll
        for (int nt = 0; nt < 4; ++nt) {
            b0[nt] = *(const f16x8*)&Bs0[(wc*64 + nt*16 + lr)*32 + lq*8];
            b1[nt] = *(const f16x8*)&Bs1[(wc*64 + nt*16 + lr)*32 + lq*8];
        }
#pragma unroll
        for (int mt = 0; mt < 4; ++mt)
#pragma unroll
            for (int nt = 0; nt < 4; ++nt) {
                acc[mt][nt] = __builtin_amdgcn_mfma_f32_16x16x32_f16(a0[mt], b0[nt], acc[mt][nt], 0, 0, 0);
                acc[mt][nt] = __builtin_amdgcn_mfma_f32_16x16x32_f16(a1[mt], b1[nt], acc[mt][nt], 0, 0, 0);
            }
    }

    size_t rowbase = (size_t)b * ch + bx * 128;
    int col0 = by * 128;
#pragma unroll
    for (int ph = 0; ph < 2; ++ph) {
        __syncthreads();
        if (wr == ph) {
#pragma unroll
            for (int mt = 0; mt < 4; ++mt)
#pragma unroll
                for (int nt = 0; nt < 4; ++nt)
#pragma unroll
                    for (int q = 0; q < 4; ++q)
                        rep[mt*16 + lq*4 + q][wc*64 + nt*16 + lr] = (f16)acc[mt][nt][q];
        }
        __syncthreads();
        int row = tid >> 2, cg = (tid & 3) * 4;
        f16* drow = Sc + (rowbase + ph*64 + row) * SEQ + col0;
        const f16* srcr = rep[row];
#pragma unroll
        for (int j = 0; j < 4; ++j)
            *(f16x8*)(drow + (cg + j)*8) = *(const f16x8*)(srcr + (cg + j)*8);
    }
}

// ---------------- in-place row softmax (normalized P, fp16) ----------------
__launch_bounds__(256, 4)
__global__ void softmax_kernel(f16* __restrict__ S) {
    int tid = threadIdx.x;
    size_t row = blockIdx.x;
    f16* p = S + row * SEQ + tid * 16;
    f16x8 v0 = ((const f16x8*)p)[0];
    f16x8 v1 = ((const f16x8*)p)[1];
    float x[16];
#pragma unroll
    for (int i = 0; i < 8; ++i) { x[i] = (float)v0[i]; x[8+i] = (float)v1[i]; }
    float mx = x[0];
#pragma unroll
    for (int i = 1; i < 16; ++i) mx = fmaxf(mx, x[i]);
#pragma unroll
    for (int m = 1; m <= 32; m <<= 1) mx = fmaxf(mx, __shfl_xor(mx, m));
    __shared__ float redm[4], redl[4];
    int w = tid >> 6;
    if ((tid & 63) == 0) redm[w] = mx;
    __syncthreads();
    mx = fmaxf(fmaxf(redm[0], redm[1]), fmaxf(redm[2], redm[3]));
    float e[16]; float se = 0.f;
#pragma unroll
    for (int i = 0; i < 16; ++i) { e[i] = __expf(x[i] - mx); se += e[i]; }
#pragma unroll
    for (int m = 1; m <= 32; m <<= 1) se += __shfl_xor(se, m);
    if ((tid & 63) == 0) redl[w] = se;
    __syncthreads();
    float inv = 1.0f / (redl[0] + redl[1] + redl[2] + redl[3]);
    f16x8 o0, o1;
#pragma unroll
    for (int i = 0; i < 8; ++i) { o0[i] = (f16)(e[i] * inv); o1[i] = (f16)(e[8+i] * inv); }
    ((f16x8*)p)[0] = o0;
    ((f16x8*)p)[1] = o1;
}

// ---------------- O = P * V^T, 128x128 tile, BK=64, XCD swizzle + LN partials ----------------
__launch_bounds__(256, 3)
__global__ void pv_kernel6(const f16* __restrict__ P, const f16* __restrict__ VT,
                           const float* __restrict__ gamma, const float* __restrict__ w_out,
                           float* __restrict__ part) {
    __shared__ __align__(16) char lds[32768];
    f16* As0 = (f16*)lds;
    f16* As1 = (f16*)(lds + 8192);
    f16* Bs0 = (f16*)(lds + 16384);
    f16* Bs1 = (f16*)(lds + 24576);

    int bx, by;
    xcd_swizzle(32, bx, by);

    int tid = threadIdx.x;
    int w = tid >> 6, l = tid & 63;
    int wr = w >> 1, wc = w & 1;
    int lr = l & 15, lq = l >> 4;
    int srow = l >> 2, skg = (l & 3) * 8;
    int b = blockIdx.z;

    const f16* Abase = P  + ((size_t)b * SEQ + bx * 128) * SEQ;
    const f16* Bbase = VT + (size_t)b * DIM * SEQ + (size_t)by * 128 * SEQ;

    f32x4 acc[4][4] = {};
    for (int k0 = 0; k0 < SEQ; k0 += 64) {
        __syncthreads();
        GLOAD16(Abase + (size_t)(w*16 + srow)*SEQ + k0 + skg,          As0 + w*512);
        GLOAD16(Abase + (size_t)((4+w)*16 + srow)*SEQ + k0 + skg,      As0 + (4+w)*512);
        GLOAD16(Abase + (size_t)(w*16 + srow)*SEQ + k0 + 32 + skg,     As1 + w*512);
        GLOAD16(Abase + (size_t)((4+w)*16 + srow)*SEQ + k0 + 32 + skg, As1 + (4+w)*512);
        GLOAD16(Bbase + (size_t)(w*16 + srow)*SEQ + k0 + skg,          Bs0 + w*512);
        GLOAD16(Bbase + (size_t)((4+w)*16 + srow)*SEQ + k0 + skg,      Bs0 + (4+w)*512);
        GLOAD16(Bbase + (size_t)(w*16 + srow)*SEQ + k0 + 32 + skg,     Bs1 + w*512);
        GLOAD16(Bbase + (size_t)((4+w)*16 + srow)*SEQ + k0 + 32 + skg, Bs1 + (4+w)*512);
        __syncthreads();
        f16x8 a0[4], b0[4], a1[4], b1[4];
#pragma unroll
        for (int mt = 0; mt < 4; ++mt) {
            a0[mt] = *(const f16x8*)&As0[(wr*64 + mt*16 + lr)*32 + lq*8];
            a1[mt] = *(const f16x8*)&As1[(wr*64 + mt*16 + lr)*32 + lq*8];
        }
#pragma unroll
        for (int nt = 0; nt < 4; ++nt) {
            b0[nt] = *(const f16x8*)&Bs0[(wc*64 + nt*16 + lr)*32 + lq*8];
            b1[nt] = *(const f16x8*)&Bs1[(wc*64 + nt*16 + lr)*32 + lq*8];
        }
#pragma unroll
        for (int mt = 0; mt < 4; ++mt)
#pragma unroll
            for (int nt = 0; nt < 4; ++nt) {
                acc[mt][nt] = __builtin_amdgcn_mfma_f32_16x16x32_f16(a0[mt], b0[nt], acc[mt][nt], 0, 0, 0);
                acc[mt][nt] = __builtin_amdgcn_mfma_f32_16x16x32_f16(a1[mt], b1[nt], acc[mt][nt], 0, 0, 0);
            }
    }

    float gw[4];
#pragma unroll
    for (int nt = 0; nt < 4; ++nt) {
        int d = by * 128 + wc*64 + nt*16 + lr;
        gw[nt] = gamma[d] * w_out[d];
    }
    int tbase = b * SEQ + bx * 128 + wr * 64;
#pragma unroll
    for (int mt = 0; mt < 4; ++mt)
#pragma unroll
        for (int q = 0; q < 4; ++q) {
            float s1 = 0.f, s2 = 0.f, s3 = 0.f;
#pragma unroll
            for (int nt = 0; nt < 4; ++nt) {
                float y = acc[mt][nt][q];
                s1 += y; s2 += y * y; s3 += y * gw[nt];
            }
#pragma unroll
            for (int m = 1; m <= 8; m <<= 1) {
                s1 += __shfl_xor(s1, m);
                s2 += __shfl_xor(s2, m);
                s3 += __shfl_xor(s3, m);
            }
            if (lr == 0) {
                int t = tbase + mt*16 + lq*4 + q;
                atomicAdd(&part[t*4 + 0], s1);
                atomicAdd(&part[t*4 + 1], s2);
                atomicAdd(&part[t*4 + 2], s3);
            }
        }
}

// ---------------- O = P * V^T (128x64 tile, BK=64) + LN partials (fallback tiers) ----------------
__launch_bounds__(256, 4)
__global__ void pv_kernel4(const f16* __restrict__ P, const f16* __restrict__ VT,
                           const float* __restrict__ gamma, const float* __restrict__ w_out,
                           float* __restrict__ part, int c0, int ch) {
    __shared__ __align__(16) char lds[24576];
    f16* As0 = (f16*)lds;
    f16* As1 = (f16*)(lds + 8192);
    f16* Bs0 = (f16*)(lds + 16384);
    f16* Bs1 = (f16*)(lds + 20480);

    int tid = threadIdx.x;
    int w = tid >> 6, l = tid & 63;
    int wr = w >> 1, wc = w & 1;
    int lr = l & 15, lq = l >> 4;
    int srow = l >> 2, skg = (l & 3) * 8;
    int b = blockIdx.z;

    const f16* Abase = P  + ((size_t)b * ch + blockIdx.x * 128) * SEQ;
    const f16* Bbase = VT + (size_t)b * DIM * SEQ + (size_t)blockIdx.y * 64 * SEQ;

    f32x4 acc[4][2] = {};
    for (int k0 = 0; k0 < SEQ; k0 += 64) {
        __syncthreads();
        GLOAD16(Abase + (size_t)(w*16 + srow)*SEQ + k0 + skg,          As0 + w*512);
        GLOAD16(Abase + (size_t)((4+w)*16 + srow)*SEQ + k0 + skg,      As0 + (4+w)*512);
        GLOAD16(Abase + (size_t)(w*16 + srow)*SEQ + k0 + 32 + skg,     As1 + w*512);
        GLOAD16(Abase + (size_t)((4+w)*16 + srow)*SEQ + k0 + 32 + skg, As1 + (4+w)*512);
        GLOAD16(Bbase + (size_t)(w*16 + srow)*SEQ + k0 + skg,          Bs0 + w*512);
        GLOAD16(Bbase + (size_t)(w*16 + srow)*SEQ + k0 + 32 + skg,     Bs1 + w*512);
        __syncthreads();
        f16x8 a0[4], a1[4], b0[2], b1[2];
#pragma unroll
        for (int mt = 0; mt < 4; ++mt) {
            a0[mt] = *(const f16x8*)&As0[(wr*64 + mt*16 + lr)*32 + lq*8];
            a1[mt] = *(const f16x8*)&As1[(wr*64 + mt*16 + lr)*32 + lq*8];
        }
#pragma unroll
        for (int nt = 0; nt < 2; ++nt) {
            b0[nt] = *(const f16x8*)&Bs0[(wc*32 + nt*16 + lr)*32 + lq*8];
            b1[nt] = *(const f16x8*)&Bs1[(wc*32 + nt*16 + lr)*32 + lq*8];
        }
#pragma unroll
        for (int mt = 0; mt < 4; ++mt)
#pragma unroll
            for (int nt = 0; nt < 2; ++nt) {
                acc[mt][nt] = __builtin_amdgcn_mfma_f32_16x16x32_f16(a0[mt], b0[nt], acc[mt][nt], 0, 0, 0);
                acc[mt][nt] = __builtin_amdgcn_mfma_f32_16x16x32_f16(a1[mt], b1[nt], acc[mt][nt], 0, 0, 0);
            }
    }

    float gw[2];
#pragma unroll
    for (int nt = 0; nt < 2; ++nt) {
        int d = blockIdx.y * 64 + wc*32 + nt*16 + lr;
        gw[nt] = gamma[d] * w_out[d];
    }
    int tbase = b * SEQ + c0 + blockIdx.x * 128 + wr * 64;
#pragma unroll
    for (int mt = 0; mt < 4; ++mt)
#pragma unroll
        for (int q = 0; q < 4; ++q) {
            float s1 = 0.f, s2 = 0.f, s3 = 0.f;
#pragma unroll
            for (int nt = 0; nt < 2; ++nt) {
                float y = acc[mt][nt][q];
                s1 += y; s2 += y * y; s3 += y * gw[nt];
            }
#pragma unroll
            for (int m = 1; m <= 8; m <<= 1) {
                s1 += __shfl_xor(s1, m);
                s2 += __shfl_xor(s2, m);
                s3 += __shfl_xor(s3, m);
            }
            if (lr == 0) {
                int t = tbase + mt*16 + lq*4 + q;
                atomicAdd(&part[t*4 + 0], s1);
                atomicAdd(&part[t*4 + 1], s2);
                atomicAdd(&part[t*4 + 2], s3);
            }
        }
}

// ---------------- finalize: LN + dot ----------------
__launch_bounds__(256)
__global__ void finalize_kernel(const float* __restrict__ part,
                                const float* __restrict__ gamma, const float* __restrict__ beta,
                                const float* __restrict__ w_out, const float* __restrict__ b_out,
                                float* __restrict__ out) {
    int tid = threadIdx.x;
    float gw = 0.f, bw = 0.f;
    for (int d = tid; d < DIM; d += 256) { gw += gamma[d] * w_out[d]; bw += beta[d] * w_out[d]; }
#pragma unroll
    for (int m = 1; m < 64; m <<= 1) { gw += __shfl_xor(gw, m); bw += __shfl_xor(bw, m); }
    __shared__ float red[8];
    if ((tid & 63) == 0) { red[(tid >> 6)*2] = gw; red[(tid >> 6)*2 + 1] = bw; }
    __syncthreads();
    float SGW = red[0] + red[2] + red[4] + red[6];
    float SBW = red[1] + red[3] + red[5] + red[7];
    int t = blockIdx.x * 256 + tid;
    float S1 = part[t*4], S2 = part[t*4 + 1], S3 = part[t*4 + 2];
    const float inv_d = 1.0f / 768.0f;
    float mu = S1 * inv_d;
    float var = S2 * inv_d - mu * mu;
    float rstd = rsqrtf(var + 1e-5f);
    out[t] = rstd * (S3 - mu * SGW) + SBW + b_out[0];
}

// ---------------- launch ----------------
extern "C" void kernel_launch(void* const* d_in, const int* in_sizes, int n_in,
                              void* d_out, int out_size, void* d_ws, size_t ws_size,
                              hipStream_t stream) {
    const float* x     = (const float*)d_in[0];
    const float* Wq    = (const float*)d_in[1];
    const float* bq    = (const float*)d_in[2];
    const float* Wk    = (const float*)d_in[3];
    const float* bk    = (const float*)d_in[4];
    const float* Wv    = (const float*)d_in[5];
    const float* bv    = (const float*)d_in[6];
    const float* gamma = (const float*)d_in[7];
    const float* beta  = (const float*)d_in[8];
    const float* w_out = (const float*)d_in[9];
    const float* b_out = (const float*)d_in[10];
    float* out = (float*)d_out;
    char* ws = (char*)d_ws;

    const size_t SZM  = 25165824;        // one 16384x768 f16 matrix
    const size_t BASE = 3 * SZM;         // after Qh|Kh|VT = 75497472
    f16* Qh = (f16*)(ws);
    f16* Kh = (f16*)(ws + SZM);
    f16* VT = (f16*)(ws + 2*SZM);

    const size_t SFULL     = 134217728;
    const size_t NEED_FULL = BASE + SFULL + 262144;
    const size_t NEED_A    = BASE + 67108864 + 3538944 + 262144;
    const size_t NEED_B    = BASE + 33554432 + SZM + 3538944 + 262144;
    const size_t NEED_C    = BASE + 33554432 + 3538944 + 262144;

    if (ws_size >= NEED_FULL) {
        f16* Sc = (f16*)(ws + BASE);
        f16* xh = (f16*)(ws + BASE);               // dead after proj
        f16* Vr = (f16*)(ws + BASE + SZM);         // dead after transpose
        f16* Wh = (f16*)(ws + BASE + 2*SZM);       // dead after proj
        float* part = (float*)(ws + BASE + SFULL);

        zero_kernel<<<256, 256, 0, stream>>>(part, 65536);
        cvt_kernel<<<2048, 256, 0, stream>>>(x, xh, TOK * DIM / 4);
        cvt_kernel<<<512, 256, 0, stream>>>(Wq, Wh,               DIM * DIM / 4);
        cvt_kernel<<<512, 256, 0, stream>>>(Wk, Wh + DIM * DIM,   DIM * DIM / 4);
        cvt_kernel<<<512, 256, 0, stream>>>(Wv, Wh + 2*DIM*DIM,   DIM * DIM / 4);

        proj_kernel4<<<dim3(TOK/128, 18), 256, 0, stream>>>(xh, Wh, bq, bk, bv, Qh, Kh, Vr, 0);
        transpose_v<<<dim3(SEQ/64, DIM/64, BATCH), 256, 0, stream>>>(Vr, VT);

        qkt_kernel4<<<dim3(SEQ/128, SEQ/128, BATCH), 256, 0, stream>>>(Qh, Kh, Sc, 0, SEQ);
        softmax_kernel<<<BATCH * SEQ, 256, 0, stream>>>(Sc);
        pv_kernel6<<<dim3(SEQ/128, DIM/128, BATCH), 256, 0, stream>>>(Sc, VT, gamma, w_out, part);
        finalize_kernel<<<TOK/256, 256, 0, stream>>>(part, gamma, beta, w_out, b_out, out);
        return;
    }

    // fallback tiers: proven round-4/6 path
    int ch; int vscatter; size_t off_wh;
    f16 *xh, *Vr, *Sc;
    if (ws_size >= NEED_A) {
        ch = 2048; vscatter = 0;
        Sc = (f16*)(ws + BASE);
        xh = (f16*)(ws + BASE);
        Vr = (f16*)(ws + BASE + SZM);
        off_wh = BASE + 67108864;
    } else if (ws_size >= NEED_B) {
        ch = 1024; vscatter = 0;
        Sc = (f16*)(ws + BASE);
        xh = (f16*)(ws + BASE);
        Vr = (f16*)(ws + BASE + 33554432);
        off_wh = BASE + 33554432 + SZM;
    } else if (ws_size >= NEED_C) {
        ch = 1024; vscatter = 1;
        Sc = (f16*)(ws + BASE);
        xh = (f16*)(ws + BASE);
        Vr = VT;
        off_wh = BASE + 33554432;
    } else {
        return;
    }
    f16* Wh = (f16*)(ws + off_wh);
    float* part = (float*)(ws + off_wh + 3538944);

    zero_kernel<<<256, 256, 0, stream>>>(part, 65536);
    cvt_kernel<<<2048, 256, 0, stream>>>(x, xh, TOK * DIM / 4);
    cvt_kernel<<<512, 256, 0, stream>>>(Wq, Wh,               DIM * DIM / 4);
    cvt_kernel<<<512, 256, 0, stream>>>(Wk, Wh + DIM * DIM,   DIM * DIM / 4);
    cvt_kernel<<<512, 256, 0, stream>>>(Wv, Wh + 2*DIM*DIM,   DIM * DIM / 4);

    proj_kernel4<<<dim3(TOK/128, 18), 256, 0, stream>>>(xh, Wh, bq, bk, bv, Qh, Kh, Vr, vscatter);
    if (!vscatter)
        transpose_v<<<dim3(SEQ/64, DIM/64, BATCH), 256, 0, stream>>>(Vr, VT);

    int nch = SEQ / ch;
    for (int c = 0; c < nch; ++c) {
        int c0 = c * ch;
        qkt_kernel4<<<dim3(ch/128, SEQ/128, BATCH), 256, 0, stream>>>(Qh, Kh, Sc, c0, ch);
        softmax_kernel<<<BATCH * ch, 256, 0, stream>>>(Sc);
        pv_kernel4<<<dim3(ch/128, DIM/64, BATCH), 256, 0, stream>>>(Sc, VT, gamma, w_out, part, c0, ch);
    }
    finalize_kernel<<<TOK/256, 256, 0, stream>>>(part, gamma, beta, w_out, b_out, out);
}

// Round 10
// 429.418 us; speedup vs baseline: 1.1875x; 1.1875x over previous
//
#include <hip/hip_runtime.h>
#include <math.h>
#include <stdint.h>

#define DIM 768
#define SEQ 4096
#define BATCH 4
#define TOK (BATCH*SEQ)

typedef _Float16 f16;
typedef _Float16 f16x8 __attribute__((ext_vector_type(8)));
typedef _Float16 f16x4 __attribute__((ext_vector_type(4)));
typedef float f32x4 __attribute__((ext_vector_type(4)));

// async global->LDS, 16B per lane; LDS dest is wave-uniform base + lane*16
#define GLOAD16(gp, lp) __builtin_amdgcn_global_load_lds( \
    (const __attribute__((address_space(1))) unsigned int*)(gp), \
    (__attribute__((address_space(3))) unsigned int*)(lp), 16, 0, 0)

// ---------------- fp32 -> fp16 convert (x) ----------------
__global__ void cvt_kernel(const float* __restrict__ src, f16* __restrict__ dst, int n4) {
    int i = blockIdx.x * blockDim.x + threadIdx.x;
    int stride = gridDim.x * blockDim.x;
    for (; i < n4; i += stride) {
        float4 v = ((const float4*)src)[i];
        f16x4 h = { (f16)v.x, (f16)v.y, (f16)v.z, (f16)v.w };
        ((f16x4*)dst)[i] = h;
    }
}

// ---------------- weights convert (Wq|Wk|Wv -> Wh) + zero part, single launch ----------------
// blocks [0, 1728): convert 3*DIM*DIM floats; blocks [1728, 1792): zero part (64K floats)
__global__ void prep_kernel(const float* __restrict__ Wq, const float* __restrict__ Wk,
                            const float* __restrict__ Wv, f16* __restrict__ Wh,
                            float* __restrict__ part) {
    const int WQUAD = DIM * DIM / 4;       // 147456 float4 groups per matrix
    int i = blockIdx.x * 256 + threadIdx.x;
    if (i < 3 * WQUAD) {
        const float* src; int j;
        if (i < WQUAD)            { src = Wq; j = i; }
        else if (i < 2 * WQUAD)   { src = Wk; j = i - WQUAD; }
        else                      { src = Wv; j = i - 2 * WQUAD; }
        float4 v = ((const float4*)src)[j];
        f16x4 h = { (f16)v.x, (f16)v.y, (f16)v.z, (f16)v.w };
        ((f16x4*)Wh)[i] = h;
    } else {
        int j = i - 3 * WQUAD;             // 16384 float4 groups of part
        if (j < 16384) {
            float4 z = {0.f, 0.f, 0.f, 0.f};
            ((float4*)part)[j] = z;
        }
    }
}

// ---------------- QKV projection GEMM (BK=64 two-subtile) ----------------
__launch_bounds__(256, 4)
__global__ void proj_kernel4(const f16* __restrict__ xh, const f16* __restrict__ Wh,
                             const float* __restrict__ bq, const float* __restrict__ bk,
                             const float* __restrict__ bv,
                             f16* __restrict__ Qh, f16* __restrict__ Kh,
                             f16* __restrict__ Vd, int vscatter) {
    __shared__ __align__(16) char lds[32768];
    f16* As0 = (f16*)lds;
    f16* As1 = (f16*)(lds + 8192);
    f16* Bs0 = (f16*)(lds + 16384);
    f16* Bs1 = (f16*)(lds + 24576);
    typedef f16 repRow[136];
    repRow* rep = (repRow*)lds;

    int tid = threadIdx.x;
    int w = tid >> 6, l = tid & 63;
    int wr = w >> 1, wc = w & 1;
    int lr = l & 15, lq = l >> 4;
    int srow = l >> 2, skg = (l & 3) * 8;

    const f16* Abase = xh + (size_t)blockIdx.x * 128 * DIM;
    const f16* Bbase = Wh + (size_t)blockIdx.y * 128 * DIM;

    f32x4 acc[4][4] = {};
    for (int k0 = 0; k0 < DIM; k0 += 64) {
        __syncthreads();
        GLOAD16(Abase + (size_t)(w*16 + srow)*DIM + k0 + skg,          As0 + w*512);
        GLOAD16(Abase + (size_t)((4+w)*16 + srow)*DIM + k0 + skg,      As0 + (4+w)*512);
        GLOAD16(Abase + (size_t)(w*16 + srow)*DIM + k0 + 32 + skg,     As1 + w*512);
        GLOAD16(Abase + (size_t)((4+w)*16 + srow)*DIM + k0 + 32 + skg, As1 + (4+w)*512);
        GLOAD16(Bbase + (size_t)(w*16 + srow)*DIM + k0 + skg,          Bs0 + w*512);
        GLOAD16(Bbase + (size_t)((4+w)*16 + srow)*DIM + k0 + skg,      Bs0 + (4+w)*512);
        GLOAD16(Bbase + (size_t)(w*16 + srow)*DIM + k0 + 32 + skg,     Bs1 + w*512);
        GLOAD16(Bbase + (size_t)((4+w)*16 + srow)*DIM + k0 + 32 + skg, Bs1 + (4+w)*512);
        __syncthreads();
        f16x8 a0[4], b0[4], a1[4], b1[4];
#pragma unroll
        for (int mt = 0; mt < 4; ++mt) {
            a0[mt] = *(const f16x8*)&As0[(wr*64 + mt*16 + lr)*32 + lq*8];
            a1[mt] = *(const f16x8*)&As1[(wr*64 + mt*16 + lr)*32 + lq*8];
        }
#pragma unroll
        for (int nt = 0; nt < 4; ++nt) {
            b0[nt] = *(const f16x8*)&Bs0[(wc*64 + nt*16 + lr)*32 + lq*8];
            b1[nt] = *(const f16x8*)&Bs1[(wc*64 + nt*16 + lr)*32 + lq*8];
        }
#pragma unroll
        for (int mt = 0; mt < 4; ++mt)
#pragma unroll
            for (int nt = 0; nt < 4; ++nt) {
                acc[mt][nt] = __builtin_amdgcn_mfma_f32_16x16x32_f16(a0[mt], b0[nt], acc[mt][nt], 0, 0, 0);
                acc[mt][nt] = __builtin_amdgcn_mfma_f32_16x16x32_f16(a1[mt], b1[nt], acc[mt][nt], 0, 0, 0);
            }
    }

    int mat = blockIdx.y / 6;
    int e0  = (blockIdx.y - mat*6) * 128;
    const float* bias = (mat == 0) ? bq : ((mat == 1) ? bk : bv);
    float be[4];
#pragma unroll
    for (int nt = 0; nt < 4; ++nt) be[nt] = bias[e0 + wc*64 + nt*16 + lr];

    int trow0 = blockIdx.x * 128;

    if (mat == 2 && vscatter) {
#pragma unroll
        for (int nt = 0; nt < 4; ++nt) {
            int e = e0 + wc*64 + nt*16 + lr;
#pragma unroll
            for (int mt = 0; mt < 4; ++mt)
#pragma unroll
                for (int q = 0; q < 4; ++q) {
                    int t = trow0 + wr*64 + mt*16 + lq*4 + q;
                    Vd[((size_t)(t >> 12) * DIM + e) * SEQ + (t & (SEQ - 1))] =
                        (f16)(acc[mt][nt][q] + be[nt]);
                }
        }
        return;
    }

    f16* dst = (mat == 0) ? Qh : ((mat == 1) ? Kh : Vd);
#pragma unroll
    for (int ph = 0; ph < 2; ++ph) {
        __syncthreads();
        if (wr == ph) {
#pragma unroll
            for (int mt = 0; mt < 4; ++mt)
#pragma unroll
                for (int nt = 0; nt < 4; ++nt)
#pragma unroll
                    for (int q = 0; q < 4; ++q)
                        rep[mt*16 + lq*4 + q][wc*64 + nt*16 + lr] = (f16)(acc[mt][nt][q] + be[nt]);
        }
        __syncthreads();
        int row = tid >> 2, cg = (tid & 3) * 4;
        f16* drow = dst + (size_t)(trow0 + ph*64 + row) * DIM + e0;
        const f16* srcr = rep[row];
#pragma unroll
        for (int j = 0; j < 4; ++j)
            *(f16x8*)(drow + (cg + j)*8) = *(const f16x8*)(srcr + (cg + j)*8);
    }
}

// ---------------- V row-major -> VT transpose (64x64 LDS tiles) ----------------
__launch_bounds__(256)
__global__ void transpose_v(const f16* __restrict__ Vr, f16* __restrict__ VT) {
    __shared__ f16 t[64][72];
    int tid = threadIdx.x;
    int b = blockIdx.z, s0 = blockIdx.x * 64, d0 = blockIdx.y * 64;
    int r = tid >> 2, c4 = tid & 3;
    const f16* src = Vr + ((size_t)b * SEQ + s0 + r) * DIM + d0;
    *(f16x8*)&t[r][c4*8]     = *(const f16x8*)(src + c4*8);
    *(f16x8*)&t[r][(c4+4)*8] = *(const f16x8*)(src + (c4+4)*8);
    __syncthreads();
    int rd = tid >> 2;
    f16* dst = VT + ((size_t)b * DIM + d0 + rd) * SEQ + s0;
#pragma unroll
    for (int c = c4; c < 8; c += 4) {
        f16x8 v;
#pragma unroll
        for (int j = 0; j < 8; ++j) v[j] = t[c*8 + j][rd];
        *(f16x8*)(dst + c*8) = v;
    }
}

// ---------------- S = Q K^T (128^2, BK=64 two-subtile) ----------------
__launch_bounds__(256, 4)
__global__ void qkt_kernel4(const f16* __restrict__ Qh, const f16* __restrict__ Kh,
                            f16* __restrict__ Sc, int c0, int ch) {
    __shared__ __align__(16) char lds[32768];
    f16* As0 = (f16*)lds;
    f16* As1 = (f16*)(lds + 8192);
    f16* Bs0 = (f16*)(lds + 16384);
    f16* Bs1 = (f16*)(lds + 24576);
    typedef f16 repRow[136];
    repRow* rep = (repRow*)lds;

    int tid = threadIdx.x;
    int w = tid >> 6, l = tid & 63;
    int wr = w >> 1, wc = w & 1;
    int lr = l & 15, lq = l >> 4;
    int srow = l >> 2, skg = (l & 3) * 8;
    int b = blockIdx.z;

    const f16* Abase = Qh + ((size_t)b * SEQ + c0 + blockIdx.x * 128) * DIM;
    const f16* Bbase = Kh + (size_t)b * SEQ * DIM + (size_t)blockIdx.y * 128 * DIM;

    f32x4 acc[4][4] = {};
    for (int k0 = 0; k0 < DIM; k0 += 64) {
        __syncthreads();
        GLOAD16(Abase + (size_t)(w*16 + srow)*DIM + k0 + skg,          As0 + w*512);
        GLOAD16(Abase + (size_t)((4+w)*16 + srow)*DIM + k0 + skg,      As0 + (4+w)*512);
        GLOAD16(Abase + (size_t)(w*16 + srow)*DIM + k0 + 32 + skg,     As1 + w*512);
        GLOAD16(Abase + (size_t)((4+w)*16 + srow)*DIM + k0 + 32 + skg, As1 + (4+w)*512);
        GLOAD16(Bbase + (size_t)(w*16 + srow)*DIM + k0 + skg,          Bs0 + w*512);
        GLOAD16(Bbase + (size_t)((4+w)*16 + srow)*DIM + k0 + skg,      Bs0 + (4+w)*512);
        GLOAD16(Bbase + (size_t)(w*16 + srow)*DIM + k0 + 32 + skg,     Bs1 + w*512);
        GLOAD16(Bbase + (size_t)((4+w)*16 + srow)*DIM + k0 + 32 + skg, Bs1 + (4+w)*512);
        __syncthreads();
        f16x8 a0[4], b0[4], a1[4], b1[4];
#pragma unroll
        for (int mt = 0; mt < 4; ++mt) {
            a0[mt] = *(const f16x8*)&As0[(wr*64 + mt*16 + lr)*32 + lq*8];
            a1[mt] = *(const f16x8*)&As1[(wr*64 + mt*16 + lr)*32 + lq*8];
        }
#pragma unroll
        for (int nt = 0; nt < 4; ++nt) {
            b0[nt] = *(const f16x8*)&Bs0[(wc*64 + nt*16 + lr)*32 + lq*8];
            b1[nt] = *(const f16x8*)&Bs1[(wc*64 + nt*16 + lr)*32 + lq*8];
        }
#pragma unroll
        for (int mt = 0; mt < 4; ++mt)
#pragma unroll
            for (int nt = 0; nt < 4; ++nt) {
                acc[mt][nt] = __builtin_amdgcn_mfma_f32_16x16x32_f16(a0[mt], b0[nt], acc[mt][nt], 0, 0, 0);
                acc[mt][nt] = __builtin_amdgcn_mfma_f32_16x16x32_f16(a1[mt], b1[nt], acc[mt][nt], 0, 0, 0);
            }
    }

    size_t rowbase = (size_t)b * ch + blockIdx.x * 128;
    int col0 = blockIdx.y * 128;
#pragma unroll
    for (int ph = 0; ph < 2; ++ph) {
        __syncthreads();
        if (wr == ph) {
#pragma unroll
            for (int mt = 0; mt < 4; ++mt)
#pragma unroll
                for (int nt = 0; nt < 4; ++nt)
#pragma unroll
                    for (int q = 0; q < 4; ++q)
                        rep[mt*16 + lq*4 + q][wc*64 + nt*16 + lr] = (f16)acc[mt][nt][q];
        }
        __syncthreads();
        int row = tid >> 2, cg = (tid & 3) * 4;
        f16* drow = Sc + (rowbase + ph*64 + row) * SEQ + col0;
        const f16* srcr = rep[row];
#pragma unroll
        for (int j = 0; j < 4; ++j)
            *(f16x8*)(drow + (cg + j)*8) = *(const f16x8*)(srcr + (cg + j)*8);
    }
}

// ---------------- in-place row softmax (normalized P, fp16) ----------------
__launch_bounds__(256, 4)
__global__ void softmax_kernel(f16* __restrict__ S) {
    int tid = threadIdx.x;
    size_t row = blockIdx.x;
    f16* p = S + row * SEQ + tid * 16;
    f16x8 v0 = ((const f16x8*)p)[0];
    f16x8 v1 = ((const f16x8*)p)[1];
    float x[16];
#pragma unroll
    for (int i = 0; i < 8; ++i) { x[i] = (float)v0[i]; x[8+i] = (float)v1[i]; }
    float mx = x[0];
#pragma unroll
    for (int i = 1; i < 16; ++i) mx = fmaxf(mx, x[i]);
#pragma unroll
    for (int m = 1; m <= 32; m <<= 1) mx = fmaxf(mx, __shfl_xor(mx, m));
    __shared__ float redm[4], redl[4];
    int w = tid >> 6;
    if ((tid & 63) == 0) redm[w] = mx;
    __syncthreads();
    mx = fmaxf(fmaxf(redm[0], redm[1]), fmaxf(redm[2], redm[3]));
    float e[16]; float se = 0.f;
#pragma unroll
    for (int i = 0; i < 16; ++i) { e[i] = __expf(x[i] - mx); se += e[i]; }
#pragma unroll
    for (int m = 1; m <= 32; m <<= 1) se += __shfl_xor(se, m);
    if ((tid & 63) == 0) redl[w] = se;
    __syncthreads();
    float inv = 1.0f / (redl[0] + redl[1] + redl[2] + redl[3]);
    f16x8 o0, o1;
#pragma unroll
    for (int i = 0; i < 8; ++i) { o0[i] = (f16)(e[i] * inv); o1[i] = (f16)(e[8+i] * inv); }
    ((f16x8*)p)[0] = o0;
    ((f16x8*)p)[1] = o1;
}

// ---------------- O = P * V^T, 128x128 tile, BK=64 + LN partials (FULL tier) ----------------
__launch_bounds__(256, 3)
__global__ void pv_kernel6(const f16* __restrict__ P, const f16* __restrict__ VT,
                           const float* __restrict__ gamma, const float* __restrict__ w_out,
                           float* __restrict__ part) {
    __shared__ __align__(16) char lds[32768];
    f16* As0 = (f16*)lds;
    f16* As1 = (f16*)(lds + 8192);
    f16* Bs0 = (f16*)(lds + 16384);
    f16* Bs1 = (f16*)(lds + 24576);

    int tid = threadIdx.x;
    int w = tid >> 6, l = tid & 63;
    int wr = w >> 1, wc = w & 1;
    int lr = l & 15, lq = l >> 4;
    int srow = l >> 2, skg = (l & 3) * 8;
    int b = blockIdx.z;

    const f16* Abase = P  + ((size_t)b * SEQ + blockIdx.x * 128) * SEQ;
    const f16* Bbase = VT + (size_t)b * DIM * SEQ + (size_t)blockIdx.y * 128 * SEQ;

    f32x4 acc[4][4] = {};
    for (int k0 = 0; k0 < SEQ; k0 += 64) {
        __syncthreads();
        GLOAD16(Abase + (size_t)(w*16 + srow)*SEQ + k0 + skg,          As0 + w*512);
        GLOAD16(Abase + (size_t)((4+w)*16 + srow)*SEQ + k0 + skg,      As0 + (4+w)*512);
        GLOAD16(Abase + (size_t)(w*16 + srow)*SEQ + k0 + 32 + skg,     As1 + w*512);
        GLOAD16(Abase + (size_t)((4+w)*16 + srow)*SEQ + k0 + 32 + skg, As1 + (4+w)*512);
        GLOAD16(Bbase + (size_t)(w*16 + srow)*SEQ + k0 + skg,          Bs0 + w*512);
        GLOAD16(Bbase + (size_t)((4+w)*16 + srow)*SEQ + k0 + skg,      Bs0 + (4+w)*512);
        GLOAD16(Bbase + (size_t)(w*16 + srow)*SEQ + k0 + 32 + skg,     Bs1 + w*512);
        GLOAD16(Bbase + (size_t)((4+w)*16 + srow)*SEQ + k0 + 32 + skg, Bs1 + (4+w)*512);
        __syncthreads();
        f16x8 a0[4], b0[4], a1[4], b1[4];
#pragma unroll
        for (int mt = 0; mt < 4; ++mt) {
            a0[mt] = *(const f16x8*)&As0[(wr*64 + mt*16 + lr)*32 + lq*8];
            a1[mt] = *(const f16x8*)&As1[(wr*64 + mt*16 + lr)*32 + lq*8];
        }
#pragma unroll
        for (int nt = 0; nt < 4; ++nt) {
            b0[nt] = *(const f16x8*)&Bs0[(wc*64 + nt*16 + lr)*32 + lq*8];
            b1[nt] = *(const f16x8*)&Bs1[(wc*64 + nt*16 + lr)*32 + lq*8];
        }
#pragma unroll
        for (int mt = 0; mt < 4; ++mt)
#pragma unroll
            for (int nt = 0; nt < 4; ++nt) {
                acc[mt][nt] = __builtin_amdgcn_mfma_f32_16x16x32_f16(a0[mt], b0[nt], acc[mt][nt], 0, 0, 0);
                acc[mt][nt] = __builtin_amdgcn_mfma_f32_16x16x32_f16(a1[mt], b1[nt], acc[mt][nt], 0, 0, 0);
            }
    }

    float gw[4];
#pragma unroll
    for (int nt = 0; nt < 4; ++nt) {
        int d = blockIdx.y * 128 + wc*64 + nt*16 + lr;
        gw[nt] = gamma[d] * w_out[d];
    }
    int tbase = b * SEQ + blockIdx.x * 128 + wr * 64;
#pragma unroll
    for (int mt = 0; mt < 4; ++mt)
#pragma unroll
        for (int q = 0; q < 4; ++q) {
            float s1 = 0.f, s2 = 0.f, s3 = 0.f;
#pragma unroll
            for (int nt = 0; nt < 4; ++nt) {
                float y = acc[mt][nt][q];
                s1 += y; s2 += y * y; s3 += y * gw[nt];
            }
#pragma unroll
            for (int m = 1; m <= 8; m <<= 1) {
                s1 += __shfl_xor(s1, m);
                s2 += __shfl_xor(s2, m);
                s3 += __shfl_xor(s3, m);
            }
            if (lr == 0) {
                int t = tbase + mt*16 + lq*4 + q;
                atomicAdd(&part[t*4 + 0], s1);
                atomicAdd(&part[t*4 + 1], s2);
                atomicAdd(&part[t*4 + 2], s3);
            }
        }
}

// ---------------- O = P * V^T (128x64 tile, BK=64) + LN partials (fallback tiers) ----------------
__launch_bounds__(256, 4)
__global__ void pv_kernel4(const f16* __restrict__ P, const f16* __restrict__ VT,
                           const float* __restrict__ gamma, const float* __restrict__ w_out,
                           float* __restrict__ part, int c0, int ch) {
    __shared__ __align__(16) char lds[24576];
    f16* As0 = (f16*)lds;
    f16* As1 = (f16*)(lds + 8192);
    f16* Bs0 = (f16*)(lds + 16384);
    f16* Bs1 = (f16*)(lds + 20480);

    int tid = threadIdx.x;
    int w = tid >> 6, l = tid & 63;
    int wr = w >> 1, wc = w & 1;
    int lr = l & 15, lq = l >> 4;
    int srow = l >> 2, skg = (l & 3) * 8;
    int b = blockIdx.z;

    const f16* Abase = P  + ((size_t)b * ch + blockIdx.x * 128) * SEQ;
    const f16* Bbase = VT + (size_t)b * DIM * SEQ + (size_t)blockIdx.y * 64 * SEQ;

    f32x4 acc[4][2] = {};
    for (int k0 = 0; k0 < SEQ; k0 += 64) {
        __syncthreads();
        GLOAD16(Abase + (size_t)(w*16 + srow)*SEQ + k0 + skg,          As0 + w*512);
        GLOAD16(Abase + (size_t)((4+w)*16 + srow)*SEQ + k0 + skg,      As0 + (4+w)*512);
        GLOAD16(Abase + (size_t)(w*16 + srow)*SEQ + k0 + 32 + skg,     As1 + w*512);
        GLOAD16(Abase + (size_t)((4+w)*16 + srow)*SEQ + k0 + 32 + skg, As1 + (4+w)*512);
        GLOAD16(Bbase + (size_t)(w*16 + srow)*SEQ + k0 + skg,          Bs0 + w*512);
        GLOAD16(Bbase + (size_t)(w*16 + srow)*SEQ + k0 + 32 + skg,     Bs1 + w*512);
        __syncthreads();
        f16x8 a0[4], a1[4], b0[2], b1[2];
#pragma unroll
        for (int mt = 0; mt < 4; ++mt) {
            a0[mt] = *(const f16x8*)&As0[(wr*64 + mt*16 + lr)*32 + lq*8];
            a1[mt] = *(const f16x8*)&As1[(wr*64 + mt*16 + lr)*32 + lq*8];
        }
#pragma unroll
        for (int nt = 0; nt < 2; ++nt) {
            b0[nt] = *(const f16x8*)&Bs0[(wc*32 + nt*16 + lr)*32 + lq*8];
            b1[nt] = *(const f16x8*)&Bs1[(wc*32 + nt*16 + lr)*32 + lq*8];
        }
#pragma unroll
        for (int mt = 0; mt < 4; ++mt)
#pragma unroll
            for (int nt = 0; nt < 2; ++nt) {
                acc[mt][nt] = __builtin_amdgcn_mfma_f32_16x16x32_f16(a0[mt], b0[nt], acc[mt][nt], 0, 0, 0);
                acc[mt][nt] = __builtin_amdgcn_mfma_f32_16x16x32_f16(a1[mt], b1[nt], acc[mt][nt], 0, 0, 0);
            }
    }

    float gw[2];
#pragma unroll
    for (int nt = 0; nt < 2; ++nt) {
        int d = blockIdx.y * 64 + wc*32 + nt*16 + lr;
        gw[nt] = gamma[d] * w_out[d];
    }
    int tbase = b * SEQ + c0 + blockIdx.x * 128 + wr * 64;
#pragma unroll
    for (int mt = 0; mt < 4; ++mt)
#pragma unroll
        for (int q = 0; q < 4; ++q) {
            float s1 = 0.f, s2 = 0.f, s3 = 0.f;
#pragma unroll
            for (int nt = 0; nt < 2; ++nt) {
                float y = acc[mt][nt][q];
                s1 += y; s2 += y * y; s3 += y * gw[nt];
            }
#pragma unroll
            for (int m = 1; m <= 8; m <<= 1) {
                s1 += __shfl_xor(s1, m);
                s2 += __shfl_xor(s2, m);
                s3 += __shfl_xor(s3, m);
            }
            if (lr == 0) {
                int t = tbase + mt*16 + lq*4 + q;
                atomicAdd(&part[t*4 + 0], s1);
                atomicAdd(&part[t*4 + 1], s2);
                atomicAdd(&part[t*4 + 2], s3);
            }
        }
}

// ---------------- finalize: LN + dot ----------------
__launch_bounds__(256)
__global__ void finalize_kernel(const float* __restrict__ part,
                                const float* __restrict__ gamma, const float* __restrict__ beta,
                                const float* __restrict__ w_out, const float* __restrict__ b_out,
                                float* __restrict__ out) {
    int tid = threadIdx.x;
    float gw = 0.f, bw = 0.f;
    for (int d = tid; d < DIM; d += 256) { gw += gamma[d] * w_out[d]; bw += beta[d] * w_out[d]; }
#pragma unroll
    for (int m = 1; m < 64; m <<= 1) { gw += __shfl_xor(gw, m); bw += __shfl_xor(bw, m); }
    __shared__ float red[8];
    if ((tid & 63) == 0) { red[(tid >> 6)*2] = gw; red[(tid >> 6)*2 + 1] = bw; }
    __syncthreads();
    float SGW = red[0] + red[2] + red[4] + red[6];
    float SBW = red[1] + red[3] + red[5] + red[7];
    int t = blockIdx.x * 256 + tid;
    float S1 = part[t*4], S2 = part[t*4 + 1], S3 = part[t*4 + 2];
    const float inv_d = 1.0f / 768.0f;
    float mu = S1 * inv_d;
    float var = S2 * inv_d - mu * mu;
    float rstd = rsqrtf(var + 1e-5f);
    out[t] = rstd * (S3 - mu * SGW) + SBW + b_out[0];
}

// ---------------- launch ----------------
extern "C" void kernel_launch(void* const* d_in, const int* in_sizes, int n_in,
                              void* d_out, int out_size, void* d_ws, size_t ws_size,
                              hipStream_t stream) {
    const float* x     = (const float*)d_in[0];
    const float* Wq    = (const float*)d_in[1];
    const float* bq    = (const float*)d_in[2];
    const float* Wk    = (const float*)d_in[3];
    const float* bk    = (const float*)d_in[4];
    const float* Wv    = (const float*)d_in[5];
    const float* bv    = (const float*)d_in[6];
    const float* gamma = (const float*)d_in[7];
    const float* beta  = (const float*)d_in[8];
    const float* w_out = (const float*)d_in[9];
    const float* b_out = (const float*)d_in[10];
    float* out = (float*)d_out;
    char* ws = (char*)d_ws;

    const size_t SZM  = 25165824;        // one 16384x768 f16 matrix
    const size_t BASE = 3 * SZM;         // after Qh|Kh|VT = 75497472
    f16* Qh = (f16*)(ws);
    f16* Kh = (f16*)(ws + SZM);
    f16* VT = (f16*)(ws + 2*SZM);

    const size_t SFULL     = 134217728;
    const size_t NEED_FULL = BASE + SFULL + 262144;
    const size_t NEED_A    = BASE + 67108864 + 3538944 + 262144;
    const size_t NEED_B    = BASE + 33554432 + SZM + 3538944 + 262144;
    const size_t NEED_C    = BASE + 33554432 + 3538944 + 262144;

    if (ws_size >= NEED_FULL) {
        f16* Sc = (f16*)(ws + BASE);
        f16* xh = (f16*)(ws + BASE);               // dead after proj
        f16* Vr = (f16*)(ws + BASE + SZM);         // dead after transpose
        f16* Wh = (f16*)(ws + BASE + 2*SZM);       // dead after proj
        float* part = (float*)(ws + BASE + SFULL);

        cvt_kernel<<<2048, 256, 0, stream>>>(x, xh, TOK * DIM / 4);
        prep_kernel<<<1792, 256, 0, stream>>>(Wq, Wk, Wv, Wh, part);

        proj_kernel4<<<dim3(TOK/128, 18), 256, 0, stream>>>(xh, Wh, bq, bk, bv, Qh, Kh, Vr, 0);
        transpose_v<<<dim3(SEQ/64, DIM/64, BATCH), 256, 0, stream>>>(Vr, VT);

        qkt_kernel4<<<dim3(SEQ/128, SEQ/128, BATCH), 256, 0, stream>>>(Qh, Kh, Sc, 0, SEQ);
        softmax_kernel<<<BATCH * SEQ, 256, 0, stream>>>(Sc);
        pv_kernel6<<<dim3(SEQ/128, DIM/128, BATCH), 256, 0, stream>>>(Sc, VT, gamma, w_out, part);
        finalize_kernel<<<TOK/256, 256, 0, stream>>>(part, gamma, beta, w_out, b_out, out);
        return;
    }

    // fallback tiers: proven round-4/6 path
    int ch; int vscatter; size_t off_wh;
    f16 *xh, *Vr, *Sc;
    if (ws_size >= NEED_A) {
        ch = 2048; vscatter = 0;
        Sc = (f16*)(ws + BASE);
        xh = (f16*)(ws + BASE);
        Vr = (f16*)(ws + BASE + SZM);
        off_wh = BASE + 67108864;
    } else if (ws_size >= NEED_B) {
        ch = 1024; vscatter = 0;
        Sc = (f16*)(ws + BASE);
        xh = (f16*)(ws + BASE);
        Vr = (f16*)(ws + BASE + 33554432);
        off_wh = BASE + 33554432 + SZM;
    } else if (ws_size >= NEED_C) {
        ch = 1024; vscatter = 1;
        Sc = (f16*)(ws + BASE);
        xh = (f16*)(ws + BASE);
        Vr = VT;
        off_wh = BASE + 33554432;
    } else {
        return;
    }
    f16* Wh = (f16*)(ws + off_wh);
    float* part = (float*)(ws + off_wh + 3538944);

    cvt_kernel<<<2048, 256, 0, stream>>>(x, xh, TOK * DIM / 4);
    prep_kernel<<<1792, 256, 0, stream>>>(Wq, Wk, Wv, Wh, part);

    proj_kernel4<<<dim3(TOK/128, 18), 256, 0, stream>>>(xh, Wh, bq, bk, bv, Qh, Kh, Vr, vscatter);
    if (!vscatter)
        transpose_v<<<dim3(SEQ/64, DIM/64, BATCH), 256, 0, stream>>>(Vr, VT);

    int nch = SEQ / ch;
    for (int c = 0; c < nch; ++c) {
        int c0 = c * ch;
        qkt_kernel4<<<dim3(ch/128, SEQ/128, BATCH), 256, 0, stream>>>(Qh, Kh, Sc, c0, ch);
        softmax_kernel<<<BATCH * ch, 256, 0, stream>>>(Sc);
        pv_kernel4<<<dim3(ch/128, DIM/64, BATCH), 256, 0, stream>>>(Sc, VT, gamma, w_out, part, c0, ch);
    }
    finalize_kernel<<<TOK/256, 256, 0, stream>>>(part, gamma, beta, w_out, b_out, out);
}

// Round 11
// 369.472 us; speedup vs baseline: 1.3802x; 1.1622x over previous
//
#include <hip/hip_runtime.h>
#include <math.h>
#include <stdint.h>

#define DIM 768
#define SEQ 4096
#define BATCH 4
#define TOK (BATCH*SEQ)

typedef _Float16 f16;
typedef _Float16 f16x8 __attribute__((ext_vector_type(8)));
typedef _Float16 f16x4 __attribute__((ext_vector_type(4)));
typedef float f32x4 __attribute__((ext_vector_type(4)));

// async global->LDS, 16B per lane; LDS dest is wave-uniform base + lane*16
#define GLOAD16(gp, lp) __builtin_amdgcn_global_load_lds( \
    (const __attribute__((address_space(1))) unsigned int*)(gp), \
    (__attribute__((address_space(3))) unsigned int*)(lp), 16, 0, 0)

// ---------------- fp32 -> fp16 convert (x) ----------------
__global__ void cvt_kernel(const float* __restrict__ src, f16* __restrict__ dst, int n4) {
    int i = blockIdx.x * blockDim.x + threadIdx.x;
    int stride = gridDim.x * blockDim.x;
    for (; i < n4; i += stride) {
        float4 v = ((const float4*)src)[i];
        f16x4 h = { (f16)v.x, (f16)v.y, (f16)v.z, (f16)v.w };
        ((f16x4*)dst)[i] = h;
    }
}

// ---------------- weights convert (Wq|Wk|Wv -> Wh) + zero part, single launch ----------------
__global__ void prep_kernel(const float* __restrict__ Wq, const float* __restrict__ Wk,
                            const float* __restrict__ Wv, f16* __restrict__ Wh,
                            float* __restrict__ part) {
    const int WQUAD = DIM * DIM / 4;       // 147456 float4 groups per matrix
    int i = blockIdx.x * 256 + threadIdx.x;
    if (i < 3 * WQUAD) {
        const float* src; int j;
        if (i < WQUAD)            { src = Wq; j = i; }
        else if (i < 2 * WQUAD)   { src = Wk; j = i - WQUAD; }
        else                      { src = Wv; j = i - 2 * WQUAD; }
        float4 v = ((const float4*)src)[j];
        f16x4 h = { (f16)v.x, (f16)v.y, (f16)v.z, (f16)v.w };
        ((f16x4*)Wh)[i] = h;
    } else {
        int j = i - 3 * WQUAD;             // 16384 float4 groups of part
        if (j < 16384) {
            float4 z = {0.f, 0.f, 0.f, 0.f};
            ((float4*)part)[j] = z;
        }
    }
}

// ---------------- QKV projection GEMM (BK=64 two-subtile) ----------------
// Q/K written row-major [t][e]; V written DIRECTLY TRANSPOSED into VT[(b*DIM+e)*SEQ + t]
__launch_bounds__(256, 3)
__global__ void proj_kernel5(const f16* __restrict__ xh, const f16* __restrict__ Wh,
                             const float* __restrict__ bq, const float* __restrict__ bk,
                             const float* __restrict__ bv,
                             f16* __restrict__ Qh, f16* __restrict__ Kh,
                             f16* __restrict__ VT) {
    __shared__ __align__(16) char lds[32768];
    f16* As0 = (f16*)lds;
    f16* As1 = (f16*)(lds + 8192);
    f16* Bs0 = (f16*)(lds + 16384);
    f16* Bs1 = (f16*)(lds + 24576);
    typedef f16 repRow[136];
    repRow* rep = (repRow*)lds;          // epilogue reuse (17408 B < 32768 B)

    int tid = threadIdx.x;
    int w = tid >> 6, l = tid & 63;
    int wr = w >> 1, wc = w & 1;
    int lr = l & 15, lq = l >> 4;
    int srow = l >> 2, skg = (l & 3) * 8;

    const f16* Abase = xh + (size_t)blockIdx.x * 128 * DIM;
    const f16* Bbase = Wh + (size_t)blockIdx.y * 128 * DIM;

    f32x4 acc[4][4] = {};
    for (int k0 = 0; k0 < DIM; k0 += 64) {
        __syncthreads();
        GLOAD16(Abase + (size_t)(w*16 + srow)*DIM + k0 + skg,          As0 + w*512);
        GLOAD16(Abase + (size_t)((4+w)*16 + srow)*DIM + k0 + skg,      As0 + (4+w)*512);
        GLOAD16(Abase + (size_t)(w*16 + srow)*DIM + k0 + 32 + skg,     As1 + w*512);
        GLOAD16(Abase + (size_t)((4+w)*16 + srow)*DIM + k0 + 32 + skg, As1 + (4+w)*512);
        GLOAD16(Bbase + (size_t)(w*16 + srow)*DIM + k0 + skg,          Bs0 + w*512);
        GLOAD16(Bbase + (size_t)((4+w)*16 + srow)*DIM + k0 + skg,      Bs0 + (4+w)*512);
        GLOAD16(Bbase + (size_t)(w*16 + srow)*DIM + k0 + 32 + skg,     Bs1 + w*512);
        GLOAD16(Bbase + (size_t)((4+w)*16 + srow)*DIM + k0 + 32 + skg, Bs1 + (4+w)*512);
        __syncthreads();
        f16x8 a0[4], b0[4], a1[4], b1[4];
#pragma unroll
        for (int mt = 0; mt < 4; ++mt) {
            a0[mt] = *(const f16x8*)&As0[(wr*64 + mt*16 + lr)*32 + lq*8];
            a1[mt] = *(const f16x8*)&As1[(wr*64 + mt*16 + lr)*32 + lq*8];
        }
#pragma unroll
        for (int nt = 0; nt < 4; ++nt) {
            b0[nt] = *(const f16x8*)&Bs0[(wc*64 + nt*16 + lr)*32 + lq*8];
            b1[nt] = *(const f16x8*)&Bs1[(wc*64 + nt*16 + lr)*32 + lq*8];
        }
#pragma unroll
        for (int mt = 0; mt < 4; ++mt)
#pragma unroll
            for (int nt = 0; nt < 4; ++nt) {
                acc[mt][nt] = __builtin_amdgcn_mfma_f32_16x16x32_f16(a0[mt], b0[nt], acc[mt][nt], 0, 0, 0);
                acc[mt][nt] = __builtin_amdgcn_mfma_f32_16x16x32_f16(a1[mt], b1[nt], acc[mt][nt], 0, 0, 0);
            }
    }

    int mat = blockIdx.y / 6;                 // 0=Q,1=K,2=V (uniform per block)
    int e0  = (blockIdx.y - mat*6) * 128;
    const float* bias = (mat == 0) ? bq : ((mat == 1) ? bk : bv);
    float be[4];
#pragma unroll
    for (int nt = 0; nt < 4; ++nt) be[nt] = bias[e0 + wc*64 + nt*16 + lr];

    int trow0 = blockIdx.x * 128;

    if (mat == 2) {
        // V: transposed repack -> coalesced VT write. rep[e_local][t_local].
        int bb = trow0 >> 12;                 // batch index (128 | 4096 so block is within one batch)
        int s0 = trow0 & (SEQ - 1);
#pragma unroll
        for (int ph = 0; ph < 2; ++ph) {      // ph = e-half
            __syncthreads();
            if (wc == ph) {
#pragma unroll
                for (int nt = 0; nt < 4; ++nt)
#pragma unroll
                    for (int mt = 0; mt < 4; ++mt)
#pragma unroll
                        for (int q = 0; q < 4; ++q)
                            rep[nt*16 + lr][wr*64 + mt*16 + lq*4 + q] = (f16)(acc[mt][nt][q] + be[nt]);
            }
            __syncthreads();
            int er = tid >> 2, cg = (tid & 3) * 32;
            f16* drow = VT + ((size_t)(bb * DIM + e0 + ph*64 + er)) * SEQ + s0 + cg;
            const f16* srcr = rep[er] + cg;
#pragma unroll
            for (int j = 0; j < 4; ++j)
                *(f16x8*)(drow + j*8) = *(const f16x8*)(srcr + j*8);
        }
        return;
    }

    f16* dst = (mat == 0) ? Qh : Kh;          // row-major [t][DIM]
#pragma unroll
    for (int ph = 0; ph < 2; ++ph) {          // ph = t-half
        __syncthreads();
        if (wr == ph) {
#pragma unroll
            for (int mt = 0; mt < 4; ++mt)
#pragma unroll
                for (int nt = 0; nt < 4; ++nt)
#pragma unroll
                    for (int q = 0; q < 4; ++q)
                        rep[mt*16 + lq*4 + q][wc*64 + nt*16 + lr] = (f16)(acc[mt][nt][q] + be[nt]);
        }
        __syncthreads();
        int row = tid >> 2, cg = (tid & 3) * 4;
        f16* drow = dst + (size_t)(trow0 + ph*64 + row) * DIM + e0;
        const f16* srcr = rep[row];
#pragma unroll
        for (int j = 0; j < 4; ++j)
            *(f16x8*)(drow + (cg + j)*8) = *(const f16x8*)(srcr + (cg + j)*8);
    }
}

// ---------------- S = Q K^T (128^2, BK=64 two-subtile) ----------------
__launch_bounds__(256, 3)
__global__ void qkt_kernel4(const f16* __restrict__ Qh, const f16* __restrict__ Kh,
                            f16* __restrict__ Sc, int c0, int ch) {
    __shared__ __align__(16) char lds[32768];
    f16* As0 = (f16*)lds;
    f16* As1 = (f16*)(lds + 8192);
    f16* Bs0 = (f16*)(lds + 16384);
    f16* Bs1 = (f16*)(lds + 24576);
    typedef f16 repRow[136];
    repRow* rep = (repRow*)lds;

    int tid = threadIdx.x;
    int w = tid >> 6, l = tid & 63;
    int wr = w >> 1, wc = w & 1;
    int lr = l & 15, lq = l >> 4;
    int srow = l >> 2, skg = (l & 3) * 8;
    int b = blockIdx.z;

    const f16* Abase = Qh + ((size_t)b * SEQ + c0 + blockIdx.x * 128) * DIM;
    const f16* Bbase = Kh + (size_t)b * SEQ * DIM + (size_t)blockIdx.y * 128 * DIM;

    f32x4 acc[4][4] = {};
    for (int k0 = 0; k0 < DIM; k0 += 64) {
        __syncthreads();
        GLOAD16(Abase + (size_t)(w*16 + srow)*DIM + k0 + skg,          As0 + w*512);
        GLOAD16(Abase + (size_t)((4+w)*16 + srow)*DIM + k0 + skg,      As0 + (4+w)*512);
        GLOAD16(Abase + (size_t)(w*16 + srow)*DIM + k0 + 32 + skg,     As1 + w*512);
        GLOAD16(Abase + (size_t)((4+w)*16 + srow)*DIM + k0 + 32 + skg, As1 + (4+w)*512);
        GLOAD16(Bbase + (size_t)(w*16 + srow)*DIM + k0 + skg,          Bs0 + w*512);
        GLOAD16(Bbase + (size_t)((4+w)*16 + srow)*DIM + k0 + skg,      Bs0 + (4+w)*512);
        GLOAD16(Bbase + (size_t)(w*16 + srow)*DIM + k0 + 32 + skg,     Bs1 + w*512);
        GLOAD16(Bbase + (size_t)((4+w)*16 + srow)*DIM + k0 + 32 + skg, Bs1 + (4+w)*512);
        __syncthreads();
        f16x8 a0[4], b0[4], a1[4], b1[4];
#pragma unroll
        for (int mt = 0; mt < 4; ++mt) {
            a0[mt] = *(const f16x8*)&As0[(wr*64 + mt*16 + lr)*32 + lq*8];
            a1[mt] = *(const f16x8*)&As1[(wr*64 + mt*16 + lr)*32 + lq*8];
        }
#pragma unroll
        for (int nt = 0; nt < 4; ++nt) {
            b0[nt] = *(const f16x8*)&Bs0[(wc*64 + nt*16 + lr)*32 + lq*8];
            b1[nt] = *(const f16x8*)&Bs1[(wc*64 + nt*16 + lr)*32 + lq*8];
        }
#pragma unroll
        for (int mt = 0; mt < 4; ++mt)
#pragma unroll
            for (int nt = 0; nt < 4; ++nt) {
                acc[mt][nt] = __builtin_amdgcn_mfma_f32_16x16x32_f16(a0[mt], b0[nt], acc[mt][nt], 0, 0, 0);
                acc[mt][nt] = __builtin_amdgcn_mfma_f32_16x16x32_f16(a1[mt], b1[nt], acc[mt][nt], 0, 0, 0);
            }
    }

    size_t rowbase = (size_t)b * ch + blockIdx.x * 128;
    int col0 = blockIdx.y * 128;
#pragma unroll
    for (int ph = 0; ph < 2; ++ph) {
        __syncthreads();
        if (wr == ph) {
#pragma unroll
            for (int mt = 0; mt < 4; ++mt)
#pragma unroll
                for (int nt = 0; nt < 4; ++nt)
#pragma unroll
                    for (int q = 0; q < 4; ++q)
                        rep[mt*16 + lq*4 + q][wc*64 + nt*16 + lr] = (f16)acc[mt][nt][q];
        }
        __syncthreads();
        int row = tid >> 2, cg = (tid & 3) * 4;
        f16* drow = Sc + (rowbase + ph*64 + row) * SEQ + col0;
        const f16* srcr = rep[row];
#pragma unroll
        for (int j = 0; j < 4; ++j)
            *(f16x8*)(drow + (cg + j)*8) = *(const f16x8*)(srcr + (cg + j)*8);
    }
}

// ---------------- in-place row softmax (normalized P, fp16) ----------------
__launch_bounds__(256, 4)
__global__ void softmax_kernel(f16* __restrict__ S) {
    int tid = threadIdx.x;
    size_t row = blockIdx.x;
    f16* p = S + row * SEQ + tid * 16;
    f16x8 v0 = ((const f16x8*)p)[0];
    f16x8 v1 = ((const f16x8*)p)[1];
    float x[16];
#pragma unroll
    for (int i = 0; i < 8; ++i) { x[i] = (float)v0[i]; x[8+i] = (float)v1[i]; }
    float mx = x[0];
#pragma unroll
    for (int i = 1; i < 16; ++i) mx = fmaxf(mx, x[i]);
#pragma unroll
    for (int m = 1; m <= 32; m <<= 1) mx = fmaxf(mx, __shfl_xor(mx, m));
    __shared__ float redm[4], redl[4];
    int w = tid >> 6;
    if ((tid & 63) == 0) redm[w] = mx;
    __syncthreads();
    mx = fmaxf(fmaxf(redm[0], redm[1]), fmaxf(redm[2], redm[3]));
    float e[16]; float se = 0.f;
#pragma unroll
    for (int i = 0; i < 16; ++i) { e[i] = __expf(x[i] - mx); se += e[i]; }
#pragma unroll
    for (int m = 1; m <= 32; m <<= 1) se += __shfl_xor(se, m);
    if ((tid & 63) == 0) redl[w] = se;
    __syncthreads();
    float inv = 1.0f / (redl[0] + redl[1] + redl[2] + redl[3]);
    f16x8 o0, o1;
#pragma unroll
    for (int i = 0; i < 8; ++i) { o0[i] = (f16)(e[i] * inv); o1[i] = (f16)(e[8+i] * inv); }
    ((f16x8*)p)[0] = o0;
    ((f16x8*)p)[1] = o1;
}

// ---------------- O = P * V^T, 128x128 tile, BK=64 + LN partials (FULL tier) ----------------
__launch_bounds__(256, 3)
__global__ void pv_kernel6(const f16* __restrict__ P, const f16* __restrict__ VT,
                           const float* __restrict__ gamma, const float* __restrict__ w_out,
                           float* __restrict__ part) {
    __shared__ __align__(16) char lds[32768];
    f16* As0 = (f16*)lds;
    f16* As1 = (f16*)(lds + 8192);
    f16* Bs0 = (f16*)(lds + 16384);
    f16* Bs1 = (f16*)(lds + 24576);

    int tid = threadIdx.x;
    int w = tid >> 6, l = tid & 63;
    int wr = w >> 1, wc = w & 1;
    int lr = l & 15, lq = l >> 4;
    int srow = l >> 2, skg = (l & 3) * 8;
    int b = blockIdx.z;

    const f16* Abase = P  + ((size_t)b * SEQ + blockIdx.x * 128) * SEQ;
    const f16* Bbase = VT + (size_t)b * DIM * SEQ + (size_t)blockIdx.y * 128 * SEQ;

    f32x4 acc[4][4] = {};
    for (int k0 = 0; k0 < SEQ; k0 += 64) {
        __syncthreads();
        GLOAD16(Abase + (size_t)(w*16 + srow)*SEQ + k0 + skg,          As0 + w*512);
        GLOAD16(Abase + (size_t)((4+w)*16 + srow)*SEQ + k0 + skg,      As0 + (4+w)*512);
        GLOAD16(Abase + (size_t)(w*16 + srow)*SEQ + k0 + 32 + skg,     As1 + w*512);
        GLOAD16(Abase + (size_t)((4+w)*16 + srow)*SEQ + k0 + 32 + skg, As1 + (4+w)*512);
        GLOAD16(Bbase + (size_t)(w*16 + srow)*SEQ + k0 + skg,          Bs0 + w*512);
        GLOAD16(Bbase + (size_t)((4+w)*16 + srow)*SEQ + k0 + skg,      Bs0 + (4+w)*512);
        GLOAD16(Bbase + (size_t)(w*16 + srow)*SEQ + k0 + 32 + skg,     Bs1 + w*512);
        GLOAD16(Bbase + (size_t)((4+w)*16 + srow)*SEQ + k0 + 32 + skg, Bs1 + (4+w)*512);
        __syncthreads();
        f16x8 a0[4], b0[4], a1[4], b1[4];
#pragma unroll
        for (int mt = 0; mt < 4; ++mt) {
            a0[mt] = *(const f16x8*)&As0[(wr*64 + mt*16 + lr)*32 + lq*8];
            a1[mt] = *(const f16x8*)&As1[(wr*64 + mt*16 + lr)*32 + lq*8];
        }
#pragma unroll
        for (int nt = 0; nt < 4; ++nt) {
            b0[nt] = *(const f16x8*)&Bs0[(wc*64 + nt*16 + lr)*32 + lq*8];
            b1[nt] = *(const f16x8*)&Bs1[(wc*64 + nt*16 + lr)*32 + lq*8];
        }
#pragma unroll
        for (int mt = 0; mt < 4; ++mt)
#pragma unroll
            for (int nt = 0; nt < 4; ++nt) {
                acc[mt][nt] = __builtin_amdgcn_mfma_f32_16x16x32_f16(a0[mt], b0[nt], acc[mt][nt], 0, 0, 0);
                acc[mt][nt] = __builtin_amdgcn_mfma_f32_16x16x32_f16(a1[mt], b1[nt], acc[mt][nt], 0, 0, 0);
            }
    }

    float gw[4];
#pragma unroll
    for (int nt = 0; nt < 4; ++nt) {
        int d = blockIdx.y * 128 + wc*64 + nt*16 + lr;
        gw[nt] = gamma[d] * w_out[d];
    }
    int tbase = b * SEQ + blockIdx.x * 128 + wr * 64;
#pragma unroll
    for (int mt = 0; mt < 4; ++mt)
#pragma unroll
        for (int q = 0; q < 4; ++q) {
            float s1 = 0.f, s2 = 0.f, s3 = 0.f;
#pragma unroll
            for (int nt = 0; nt < 4; ++nt) {
                float y = acc[mt][nt][q];
                s1 += y; s2 += y * y; s3 += y * gw[nt];
            }
#pragma unroll
            for (int m = 1; m <= 8; m <<= 1) {
                s1 += __shfl_xor(s1, m);
                s2 += __shfl_xor(s2, m);
                s3 += __shfl_xor(s3, m);
            }
            if (lr == 0) {
                int t = tbase + mt*16 + lq*4 + q;
                atomicAdd(&part[t*4 + 0], s1);
                atomicAdd(&part[t*4 + 1], s2);
                atomicAdd(&part[t*4 + 2], s3);
            }
        }
}

// ---------------- O = P * V^T (128x64 tile, BK=64) + LN partials (fallback tiers) ----------------
__launch_bounds__(256, 4)
__global__ void pv_kernel4(const f16* __restrict__ P, const f16* __restrict__ VT,
                           const float* __restrict__ gamma, const float* __restrict__ w_out,
                           float* __restrict__ part, int c0, int ch) {
    __shared__ __align__(16) char lds[24576];
    f16* As0 = (f16*)lds;
    f16* As1 = (f16*)(lds + 8192);
    f16* Bs0 = (f16*)(lds + 16384);
    f16* Bs1 = (f16*)(lds + 20480);

    int tid = threadIdx.x;
    int w = tid >> 6, l = tid & 63;
    int wr = w >> 1, wc = w & 1;
    int lr = l & 15, lq = l >> 4;
    int srow = l >> 2, skg = (l & 3) * 8;
    int b = blockIdx.z;

    const f16* Abase = P  + ((size_t)b * ch + blockIdx.x * 128) * SEQ;
    const f16* Bbase = VT + (size_t)b * DIM * SEQ + (size_t)blockIdx.y * 64 * SEQ;

    f32x4 acc[4][2] = {};
    for (int k0 = 0; k0 < SEQ; k0 += 64) {
        __syncthreads();
        GLOAD16(Abase + (size_t)(w*16 + srow)*SEQ + k0 + skg,          As0 + w*512);
        GLOAD16(Abase + (size_t)((4+w)*16 + srow)*SEQ + k0 + skg,      As0 + (4+w)*512);
        GLOAD16(Abase + (size_t)(w*16 + srow)*SEQ + k0 + 32 + skg,     As1 + w*512);
        GLOAD16(Abase + (size_t)((4+w)*16 + srow)*SEQ + k0 + 32 + skg, As1 + (4+w)*512);
        GLOAD16(Bbase + (size_t)(w*16 + srow)*SEQ + k0 + skg,          Bs0 + w*512);
        GLOAD16(Bbase + (size_t)(w*16 + srow)*SEQ + k0 + 32 + skg,     Bs1 + w*512);
        __syncthreads();
        f16x8 a0[4], a1[4], b0[2], b1[2];
#pragma unroll
        for (int mt = 0; mt < 4; ++mt) {
            a0[mt] = *(const f16x8*)&As0[(wr*64 + mt*16 + lr)*32 + lq*8];
            a1[mt] = *(const f16x8*)&As1[(wr*64 + mt*16 + lr)*32 + lq*8];
        }
#pragma unroll
        for (int nt = 0; nt < 2; ++nt) {
            b0[nt] = *(const f16x8*)&Bs0[(wc*32 + nt*16 + lr)*32 + lq*8];
            b1[nt] = *(const f16x8*)&Bs1[(wc*32 + nt*16 + lr)*32 + lq*8];
        }
#pragma unroll
        for (int mt = 0; mt < 4; ++mt)
#pragma unroll
            for (int nt = 0; nt < 2; ++nt) {
                acc[mt][nt] = __builtin_amdgcn_mfma_f32_16x16x32_f16(a0[mt], b0[nt], acc[mt][nt], 0, 0, 0);
                acc[mt][nt] = __builtin_amdgcn_mfma_f32_16x16x32_f16(a1[mt], b1[nt], acc[mt][nt], 0, 0, 0);
            }
    }

    float gw[2];
#pragma unroll
    for (int nt = 0; nt < 2; ++nt) {
        int d = blockIdx.y * 64 + wc*32 + nt*16 + lr;
        gw[nt] = gamma[d] * w_out[d];
    }
    int tbase = b * SEQ + c0 + blockIdx.x * 128 + wr * 64;
#pragma unroll
    for (int mt = 0; mt < 4; ++mt)
#pragma unroll
        for (int q = 0; q < 4; ++q) {
            float s1 = 0.f, s2 = 0.f, s3 = 0.f;
#pragma unroll
            for (int nt = 0; nt < 2; ++nt) {
                float y = acc[mt][nt][q];
                s1 += y; s2 += y * y; s3 += y * gw[nt];
            }
#pragma unroll
            for (int m = 1; m <= 8; m <<= 1) {
                s1 += __shfl_xor(s1, m);
                s2 += __shfl_xor(s2, m);
                s3 += __shfl_xor(s3, m);
            }
            if (lr == 0) {
                int t = tbase + mt*16 + lq*4 + q;
                atomicAdd(&part[t*4 + 0], s1);
                atomicAdd(&part[t*4 + 1], s2);
                atomicAdd(&part[t*4 + 2], s3);
            }
        }
}

// ---------------- finalize: LN + dot ----------------
__launch_bounds__(256)
__global__ void finalize_kernel(const float* __restrict__ part,
                                const float* __restrict__ gamma, const float* __restrict__ beta,
                                const float* __restrict__ w_out, const float* __restrict__ b_out,
                                float* __restrict__ out) {
    int tid = threadIdx.x;
    float gw = 0.f, bw = 0.f;
    for (int d = tid; d < DIM; d += 256) { gw += gamma[d] * w_out[d]; bw += beta[d] * w_out[d]; }
#pragma unroll
    for (int m = 1; m < 64; m <<= 1) { gw += __shfl_xor(gw, m); bw += __shfl_xor(bw, m); }
    __shared__ float red[8];
    if ((tid & 63) == 0) { red[(tid >> 6)*2] = gw; red[(tid >> 6)*2 + 1] = bw; }
    __syncthreads();
    float SGW = red[0] + red[2] + red[4] + red[6];
    float SBW = red[1] + red[3] + red[5] + red[7];
    int t = blockIdx.x * 256 + tid;
    float S1 = part[t*4], S2 = part[t*4 + 1], S3 = part[t*4 + 2];
    const float inv_d = 1.0f / 768.0f;
    float mu = S1 * inv_d;
    float var = S2 * inv_d - mu * mu;
    float rstd = rsqrtf(var + 1e-5f);
    out[t] = rstd * (S3 - mu * SGW) + SBW + b_out[0];
}

// ---------------- launch ----------------
extern "C" void kernel_launch(void* const* d_in, const int* in_sizes, int n_in,
                              void* d_out, int out_size, void* d_ws, size_t ws_size,
                              hipStream_t stream) {
    const float* x     = (const float*)d_in[0];
    const float* Wq    = (const float*)d_in[1];
    const float* bq    = (const float*)d_in[2];
    const float* Wk    = (const float*)d_in[3];
    const float* bk    = (const float*)d_in[4];
    const float* Wv    = (const float*)d_in[5];
    const float* bv    = (const float*)d_in[6];
    const float* gamma = (const float*)d_in[7];
    const float* beta  = (const float*)d_in[8];
    const float* w_out = (const float*)d_in[9];
    const float* b_out = (const float*)d_in[10];
    float* out = (float*)d_out;
    char* ws = (char*)d_ws;

    const size_t SZM  = 25165824;        // one 16384x768 f16 matrix
    const size_t BASE = 3 * SZM;         // after Qh|Kh|VT = 75497472
    f16* Qh = (f16*)(ws);
    f16* Kh = (f16*)(ws + SZM);
    f16* VT = (f16*)(ws + 2*SZM);

    const size_t SFULL     = 134217728;
    const size_t NEED_FULL = BASE + SFULL + 262144;                 // 209977344
    const size_t NEED_A    = BASE + 67108864 + 3538944 + 262144;    // ch=2048
    const size_t NEED_C    = BASE + 33554432 + 3538944 + 262144;    // ch=1024

    if (ws_size >= NEED_FULL) {
        f16* Sc = (f16*)(ws + BASE);
        f16* xh = (f16*)(ws + BASE);               // dead after proj
        f16* Wh = (f16*)(ws + BASE + SZM);         // dead after proj
        float* part = (float*)(ws + BASE + SFULL);

        cvt_kernel<<<2048, 256, 0, stream>>>(x, xh, TOK * DIM / 4);
        prep_kernel<<<1792, 256, 0, stream>>>(Wq, Wk, Wv, Wh, part);

        proj_kernel5<<<dim3(TOK/128, 18), 256, 0, stream>>>(xh, Wh, bq, bk, bv, Qh, Kh, VT);

        qkt_kernel4<<<dim3(SEQ/128, SEQ/128, BATCH), 256, 0, stream>>>(Qh, Kh, Sc, 0, SEQ);
        softmax_kernel<<<BATCH * SEQ, 256, 0, stream>>>(Sc);
        pv_kernel6<<<dim3(SEQ/128, DIM/128, BATCH), 256, 0, stream>>>(Sc, VT, gamma, w_out, part);
        finalize_kernel<<<TOK/256, 256, 0, stream>>>(part, gamma, beta, w_out, b_out, out);
        return;
    }

    // fallback tiers (chunked S), same kernels
    int ch; size_t off_wh;
    if (ws_size >= NEED_A)      { ch = 2048; off_wh = BASE + 67108864; }
    else if (ws_size >= NEED_C) { ch = 1024; off_wh = BASE + 33554432; }
    else return;                 // insufficient workspace: visible failure

    f16* Sc = (f16*)(ws + BASE);
    f16* xh = (f16*)(ws + BASE);
    f16* Wh = (f16*)(ws + off_wh);
    float* part = (float*)(ws + off_wh + 3538944);

    cvt_kernel<<<2048, 256, 0, stream>>>(x, xh, TOK * DIM / 4);
    prep_kernel<<<1792, 256, 0, stream>>>(Wq, Wk, Wv, Wh, part);

    proj_kernel5<<<dim3(TOK/128, 18), 256, 0, stream>>>(xh, Wh, bq, bk, bv, Qh, Kh, VT);

    int nch = SEQ / ch;
    for (int c = 0; c < nch; ++c) {
        int c0 = c * ch;
        qkt_kernel4<<<dim3(ch/128, SEQ/128, BATCH), 256, 0, stream>>>(Qh, Kh, Sc, c0, ch);
        softmax_kernel<<<BATCH * ch, 256, 0, stream>>>(Sc);
        pv_kernel4<<<dim3(ch/128, DIM/64, BATCH), 256, 0, stream>>>(Sc, VT, gamma, w_out, part, c0, ch);
    }
    finalize_kernel<<<TOK/256, 256, 0, stream>>>(part, gamma, beta, w_out, b_out, out);
}